// Round 13
// baseline (656.662 us; speedup 1.0000x reference)
//
#include <hip/hip_runtime.h>
#include <math.h>

#define NN 50000
#define NE 800000
#define NG 1024
#define HID 128

typedef __attribute__((ext_vector_type(8))) short short8;
typedef __attribute__((ext_vector_type(4))) unsigned short ushort4v;
typedef __attribute__((ext_vector_type(4))) float f32x4;

__device__ __forceinline__ float leakyf(float v){ return v >= 0.f ? v : 0.01f*v; }
__device__ __forceinline__ float frcp(float x){ return __builtin_amdgcn_rcpf(x); }
__device__ __forceinline__ float fsigm(float v){ return frcp(1.f + __expf(-v)); }
__device__ __forceinline__ float ftanh(float v){ return 1.f - 2.f*frcp(1.f + __expf(2.f*v)); }
__device__ __forceinline__ float eluf(float v){ return v > 0.f ? v : __expf(v) - 1.f; }
__device__ __forceinline__ unsigned short bf16rne(float f){
  union { float f; unsigned u; } v; v.f = f;
  return (unsigned short)((v.u + 0x7FFFu + ((v.u >> 16) & 1u)) >> 16);
}
__device__ __forceinline__ float bf2f(unsigned short h){
  union { unsigned u; float f; } v; v.u = ((unsigned)h) << 16; return v.f;
}
__device__ __forceinline__ short8 cvt8(const float* a){
  short8 r;
#pragma unroll
  for (int j=0;j<8;j++) r[j] = (short)bf16rne(a[j]);
  return r;
}

// ======== pack weights + all small prep, one dispatch ================================
// m=0..11: MFMA B-frag packs; m=12: readout GRU k-quad pack; m=13: cg/vmd/goff prep
__global__ __launch_bounds__(256)
void pack_all(const float* W1, const float* Wg1, const float* Wg2, const float* Wa,
              const float* Wm, const float* Wih0, const float* Whh0,
              const float* Wih_a, const float* Whh_a,
              const float* Wih_m, const float* Whh_m, const float* att_dst_m,
              const int* __restrict__ batch,
              unsigned short* __restrict__ dst,
              unsigned short* __restrict__ Wit, unsigned short* __restrict__ Wht,
              float* __restrict__ cg, float* __restrict__ vmd,
              int* __restrict__ goff)
{
  int m = (int)blockIdx.y;
  int tid = (int)threadIdx.x;
  if (m == 12){
    for (int it = (int)blockIdx.x*256 + tid; it < 32*384; it += 24*256){
      int q = it / 384, cg2 = it - q*384;
      ushort4v a, b;
#pragma unroll
      for (int j=0;j<4;j++){
        a[j] = bf16rne(Wih_m[(size_t)cg2*128 + q*4 + j]);
        b[j] = bf16rne(Whh_m[(size_t)cg2*128 + q*4 + j]);
      }
      *(ushort4v*)&Wit[((size_t)q*384 + cg2)*4] = a;
      *(ushort4v*)&Wht[((size_t)q*384 + cg2)*4] = b;
    }
    return;
  }
  if (m == 13){
    if (blockIdx.x == 0){
      if (tid < 128){
        float s = 0.f;
        for (int k=128;k<153;k++) s += Wg1[(size_t)tid*153+k];
        cg[tid] = s;
      } else {
        int k = tid - 128;
        float s = 0.f;
        for (int j=0;j<HID;j++) s += Wm[(size_t)j*HID+k]*att_dst_m[j];
        vmd[k] = s;
      }
    } else {
      int g = ((int)blockIdx.x-1)*256 + tid;
      if (g <= NG){
        int lo=0, hi=NN;
        while (lo<hi){ int mid=(lo+hi)>>1; if (batch[mid] < g) lo=mid+1; else hi=mid; }
        goff[g] = lo;
      }
    }
    return;
  }
  int t = (int)blockIdx.x*4 + (tid>>6);
  int l = tid & 63;
  const float* src; int stride=128, M=128, K=128; size_t doff;
  switch(m){
    case 0:  src=W1;    stride=64;  K=64;  doff=0;      break;
    case 1:  src=Wg1;   stride=153;        doff=8192;   break;
    case 2:  src=Wg2;                      doff=24576;  break;
    case 3:  src=Wa;                       doff=40960;  break;
    case 4:  src=Wa+16384;                 doff=57344;  break;
    case 5:  src=Wm;                       doff=73728;  break;
    case 6:  src=Wih0;  M=384;             doff=90112;  break;
    case 7:  src=Whh0;  M=384;             doff=139264; break;
    case 8:  src=Wih_a; M=384;             doff=188416; break;
    case 9:  src=Whh_a; M=384;             doff=237568; break;
    case 10: src=Wih_a+49152; M=384;       doff=286720; break;
    default: src=Whh_a+49152; M=384;       doff=335872; break;
  }
  int tk = K/32;
  if (t >= (M/16)*tk) return;
  int ct = t / tk, kc = t % tk;
  int row = ct*16 + (l&15);
  int col = kc*32 + ((l>>4)<<3);
  unsigned short o[8];
#pragma unroll
  for (int j=0;j<8;j++) o[j] = bf16rne(src[(size_t)row*stride + col + j]);
  ushort4v* d = (ushort4v*)(dst + doff + (((size_t)t*64 + l)<<3));
  ushort4v d0; d0.x=o[0]; d0.y=o[1]; d0.z=o[2]; d0.w=o[3];
  ushort4v d1; d1.x=o[4]; d1.y=o[5]; d1.z=o[6]; d1.w=o[7];
  d[0]=d0; d[1]=d1;
}

// ======== gemm_f32: fp32 A (first layer only, K=64), dual fp32+bf16 C out ============
__global__ __launch_bounds__(256)
void gemm_f32(const float* __restrict__ A, const unsigned short* __restrict__ Wp,
              const float* __restrict__ bias, float* __restrict__ Cf,
              unsigned short* __restrict__ Cb, int rows, int act)
{
  constexpr int K = 64, KC = 2;
  const int tid=(int)threadIdx.x, w=tid>>6, l=tid&63;
  const int fr=l&15, fq=l>>4;
  const int rt=w>>1, ch=w&1;
  const int bn = (int)blockIdx.x*32;
  const int ar = bn + rt*16 + fr;
  f32x4 acc[4];
#pragma unroll
  for (int j=0;j<4;j++) acc[j] = (f32x4){0.f,0.f,0.f,0.f};
#pragma unroll
  for (int kc=0;kc<KC;kc++){
    float a8[8];
    if (ar < rows){
      *(float4*)&a8[0] = *(const float4*)(A + (size_t)ar*K + kc*32 + fq*8);
      *(float4*)&a8[4] = *(const float4*)(A + (size_t)ar*K + kc*32 + fq*8 + 4);
    } else {
#pragma unroll
      for (int j=0;j<8;j++) a8[j]=0.f;
    }
    short8 fa = cvt8(a8);
#pragma unroll
    for (int j=0;j<4;j++){
      const short8 bfr = *(const short8*)(Wp + ((((size_t)(ch*4+j)*KC + kc)*64 + l)<<3));
      acc[j] = __builtin_amdgcn_mfma_f32_16x16x32_bf16(fa, bfr, acc[j], 0, 0, 0);
    }
  }
#pragma unroll
  for (int j=0;j<4;j++){
    int c = ch*64 + j*16 + fr;
    float bv = bias ? bias[c] : 0.f;
#pragma unroll
    for (int r4=0;r4<4;r4++){
      float o = acc[j][r4] + bv;
      if (act) o = leakyf(o);
      int r = bn + rt*16 + fq*4 + r4;
      if (r < rows){
        Cf[(size_t)r*HID + c] = o;
        Cb[(size_t)r*HID + c] = bf16rne(o);
      }
    }
  }
}

// ======== gemm_b16: bf16 A (128-K), optional bf16 C, fused attention dots ============
__global__ __launch_bounds__(256)
void gemm_b16(const unsigned short* __restrict__ Ab, const unsigned short* __restrict__ Wp,
              const float* __restrict__ bias, unsigned short* __restrict__ Cb,
              const float* __restrict__ v1, const float* __restrict__ v2,
              float* __restrict__ s1, float* __restrict__ s2, int rows, int act)
{
  __shared__ float sd1[2][32];
  __shared__ float sd2[2][32];
  constexpr int KC = 4;
  const int tid=(int)threadIdx.x, w=tid>>6, l=tid&63;
  const int fr=l&15, fq=l>>4;
  const int rt=w>>1, ch=w&1;
  const int bn = (int)blockIdx.x*32;
  const int ar = bn + rt*16 + fr;
  f32x4 acc[4];
#pragma unroll
  for (int j=0;j<4;j++) acc[j] = (f32x4){0.f,0.f,0.f,0.f};
#pragma unroll
  for (int kc=0;kc<KC;kc++){
    short8 fa;
    if (ar < rows) fa = *(const short8*)(Ab + (size_t)ar*HID + kc*32 + fq*8);
    else { short8 z = {0,0,0,0,0,0,0,0}; fa = z; }
#pragma unroll
    for (int j=0;j<4;j++){
      const short8 bfr = *(const short8*)(Wp + ((((size_t)(ch*4+j)*KC + kc)*64 + l)<<3));
      acc[j] = __builtin_amdgcn_mfma_f32_16x16x32_bf16(fa, bfr, acc[j], 0, 0, 0);
    }
  }
  float dp1[4]={0.f,0.f,0.f,0.f}, dp2[4]={0.f,0.f,0.f,0.f};
#pragma unroll
  for (int j=0;j<4;j++){
    int c = ch*64 + j*16 + fr;
    float bv = bias ? bias[c] : 0.f;
    float w1 = v1 ? v1[c] : 0.f;
    float w2 = v2 ? v2[c] : 0.f;
#pragma unroll
    for (int r4=0;r4<4;r4++){
      float o = acc[j][r4] + bv;
      if (act) o = leakyf(o);
      dp1[r4] += o*w1; dp2[r4] += o*w2;
      int r = bn + rt*16 + fq*4 + r4;
      if (r < rows && Cb) Cb[(size_t)r*HID + c] = bf16rne(o);
    }
  }
  if (v1){
#pragma unroll
    for (int r4=0;r4<4;r4++){
#pragma unroll
      for (int m=1;m<16;m<<=1){ dp1[r4] += __shfl_xor(dp1[r4], m); dp2[r4] += __shfl_xor(dp2[r4], m); }
    }
    if (fr==0){
#pragma unroll
      for (int r4=0;r4<4;r4++){
        sd1[ch][rt*16 + fq*4 + r4] = dp1[r4];
        sd2[ch][rt*16 + fq*4 + r4] = dp2[r4];
      }
    }
    __syncthreads();
    if (tid < 32){
      int r = bn + tid;
      if (r < rows) s1[r] = sd1[0][tid] + sd1[1][tid];
    } else if (v2 && tid < 64){
      int r = bn + tid - 32;
      if (r < rows) s2[r] = sd2[0][tid-32] + sd2[1][tid-32];
    }
  }
}

// ======== gemm_gate: GATEConv merged pass ===========================================
__global__ __launch_bounds__(256)
void gemm_gate(const unsigned short* __restrict__ Ab,
               const unsigned short* __restrict__ W1p, const unsigned short* __restrict__ W2p,
               const float* __restrict__ cg, const float* __restrict__ attl,
               const float* __restrict__ attr,
               unsigned short* __restrict__ Cb,
               float* __restrict__ s1, float* __restrict__ s2, int rows)
{
  __shared__ float sd1[2][32];
  constexpr int KC = 4;
  const int tid=(int)threadIdx.x, w=tid>>6, l=tid&63;
  const int fr=l&15, fq=l>>4;
  const int rt=w>>1, ch=w&1;
  const int bn = (int)blockIdx.x*32;
  const int ar = bn + rt*16 + fr;
  f32x4 acc1[4], acc2[4];
#pragma unroll
  for (int j=0;j<4;j++){ acc1[j]=(f32x4){0,0,0,0}; acc2[j]=(f32x4){0,0,0,0}; }
  float pa = 0.f;
#pragma unroll
  for (int kc=0;kc<KC;kc++){
    short8 fa;
    if (ar < rows) fa = *(const short8*)(Ab + (size_t)ar*HID + kc*32 + fq*8);
    else { short8 z = {0,0,0,0,0,0,0,0}; fa = z; }
    if (ch==0){
      float4 t0 = *(const float4*)(attr + kc*32 + fq*8);
      float4 t1 = *(const float4*)(attr + kc*32 + fq*8 + 4);
      pa += bf2f((unsigned short)fa[0])*t0.x + bf2f((unsigned short)fa[1])*t0.y
          + bf2f((unsigned short)fa[2])*t0.z + bf2f((unsigned short)fa[3])*t0.w
          + bf2f((unsigned short)fa[4])*t1.x + bf2f((unsigned short)fa[5])*t1.y
          + bf2f((unsigned short)fa[6])*t1.z + bf2f((unsigned short)fa[7])*t1.w;
    }
#pragma unroll
    for (int j=0;j<4;j++){
      size_t wo = ((((size_t)(ch*4+j)*KC + kc)*64 + l)<<3);
      acc1[j] = __builtin_amdgcn_mfma_f32_16x16x32_bf16(fa, *(const short8*)(W1p + wo), acc1[j], 0, 0, 0);
      acc2[j] = __builtin_amdgcn_mfma_f32_16x16x32_bf16(fa, *(const short8*)(W2p + wo), acc2[j], 0, 0, 0);
    }
  }
  float dp1[4]={0.f,0.f,0.f,0.f};
#pragma unroll
  for (int j=0;j<4;j++){
    int c = ch*64 + j*16 + fr;
    float bv = cg[c];
    float w1 = attl[c];
#pragma unroll
    for (int r4=0;r4<4;r4++){
      float o1 = leakyf(acc1[j][r4] + bv);
      dp1[r4] += o1*w1;
      int r = bn + rt*16 + fq*4 + r4;
      if (r < rows) Cb[(size_t)r*HID + c] = bf16rne(acc2[j][r4]);
    }
  }
#pragma unroll
  for (int r4=0;r4<4;r4++){
#pragma unroll
    for (int m=1;m<16;m<<=1) dp1[r4] += __shfl_xor(dp1[r4], m);
  }
  if (fr==0){
#pragma unroll
    for (int r4=0;r4<4;r4++) sd1[ch][rt*16 + fq*4 + r4] = dp1[r4];
  }
  __syncthreads();
  if (tid < 32){
    int r = bn + tid;
    if (r < rows) s1[r] = sd1[0][tid] + sd1[1][tid];
  }
  if (ch==0){
    pa += __shfl_xor(pa, 16); pa += __shfl_xor(pa, 32);
    if (fq==0){
      int r = bn + rt*16 + fr;
      if (r < rows) s2[r] = pa;
    }
  }
}

// ======== fused GRU: reg weights, 4 tiles/block, full prefetch (incl. hv) ===========
#define GRU_TPB 4
__global__ __launch_bounds__(512, 2)
void fused_gru(const unsigned short* __restrict__ Ahb, const unsigned short* __restrict__ Axb,
               const float* __restrict__ Axf,
               const unsigned short* __restrict__ Wi, const unsigned short* __restrict__ Wh,
               const float* __restrict__ bih, const float* __restrict__ bhh,
               float* __restrict__ outf, unsigned short* __restrict__ outb, int tiles)
{
  const int tid=(int)threadIdx.x, w=tid>>6, l=tid&63;
  const int fr=l&15, fq=l>>4;
  short8 wi_r[3][4], wh_r[3][4];
#pragma unroll
  for (int g=0;g<3;g++)
#pragma unroll
    for (int kc=0;kc<4;kc++){
      size_t o = ((((size_t)(g*8 + w)*4 + kc)*64 + l)<<3);
      wi_r[g][kc] = *(const short8*)(Wi + o);
      wh_r[g][kc] = *(const short8*)(Wh + o);
    }
  const int c0 = w*16 + fr;
  float bi0=bih[c0], bi1=bih[c0+128], bi2=bih[c0+256];
  float bh0=bhh[c0], bh1=bhh[c0+128], bh2=bhh[c0+256];

  int rt = (int)blockIdx.x*GRU_TPB;
  int rt_end = min(rt + GRU_TPB, tiles);
  if (rt >= tiles) return;
  short8 fa[4], fx[4];
  float hv[4];
  {
    const int arow = rt*16 + fr;
#pragma unroll
    for (int kc=0;kc<4;kc++){
      fa[kc] = *(const short8*)(Ahb + (size_t)arow*HID + kc*32 + fq*8);
      fx[kc] = *(const short8*)(Axb + (size_t)arow*HID + kc*32 + fq*8);
    }
#pragma unroll
    for (int r4=0;r4<4;r4++) hv[r4] = Axf[(size_t)(rt*16 + fq*4 + r4)*HID + c0];
  }
  for (; rt < rt_end; rt++){
    short8 nfa[4], nfx[4];
    float nhv[4];
    if (rt+1 < rt_end){
      const int arow = (rt+1)*16 + fr;
#pragma unroll
      for (int kc=0;kc<4;kc++){
        nfa[kc] = *(const short8*)(Ahb + (size_t)arow*HID + kc*32 + fq*8);
        nfx[kc] = *(const short8*)(Axb + (size_t)arow*HID + kc*32 + fq*8);
      }
#pragma unroll
      for (int r4=0;r4<4;r4++) nhv[r4] = Axf[(size_t)((rt+1)*16 + fq*4 + r4)*HID + c0];
    }
    f32x4 ai0={0,0,0,0}, ai1={0,0,0,0}, ai2={0,0,0,0};
    f32x4 ah0={0,0,0,0}, ah1={0,0,0,0}, ah2={0,0,0,0};
#pragma unroll
    for (int kc=0;kc<4;kc++){
      ai0 = __builtin_amdgcn_mfma_f32_16x16x32_bf16(fa[kc], wi_r[0][kc], ai0, 0, 0, 0);
      ai1 = __builtin_amdgcn_mfma_f32_16x16x32_bf16(fa[kc], wi_r[1][kc], ai1, 0, 0, 0);
      ai2 = __builtin_amdgcn_mfma_f32_16x16x32_bf16(fa[kc], wi_r[2][kc], ai2, 0, 0, 0);
      ah0 = __builtin_amdgcn_mfma_f32_16x16x32_bf16(fx[kc], wh_r[0][kc], ah0, 0, 0, 0);
      ah1 = __builtin_amdgcn_mfma_f32_16x16x32_bf16(fx[kc], wh_r[1][kc], ah1, 0, 0, 0);
      ah2 = __builtin_amdgcn_mfma_f32_16x16x32_bf16(fx[kc], wh_r[2][kc], ah2, 0, 0, 0);
    }
#pragma unroll
    for (int r4=0;r4<4;r4++){
      int row = rt*16 + fq*4 + r4;
      float rr = fsigm(ai0[r4] + bi0 + ah0[r4] + bh0);
      float zz = fsigm(ai1[r4] + bi1 + ah1[r4] + bh1);
      float nn = ftanh(ai2[r4] + bi2 + rr*(ah2[r4] + bh2));
      float o = fmaxf((1.f - zz)*nn + zz*hv[r4], 0.f);
      outf[(size_t)row*HID + c0] = o;
      outb[(size_t)row*HID + c0] = bf16rne(o);
    }
#pragma unroll
    for (int kc=0;kc<4;kc++){ fa[kc]=nfa[kc]; fx[kc]=nfx[kc]; }
#pragma unroll
    for (int r4=0;r4<4;r4++) hv[r4]=nhv[r4];
  }
}

// ================= CSR build =========================================================
__global__ void count_kernel(const int* __restrict__ idx, int* __restrict__ cnt, int n){
  int i = (int)(blockIdx.x*blockDim.x + threadIdx.x);
  if (i < n) atomicAdd(&cnt[idx[i]], 1);
}

__global__ __launch_bounds__(1024)
void scan_blocks(const int* __restrict__ cnt, int* __restrict__ off,
                 int* __restrict__ tot, int n)
{
  __shared__ int buf[1024];
  int i = (int)(blockIdx.x*1024 + threadIdx.x);
  int v = (i<n)? cnt[i] : 0;
  buf[threadIdx.x] = v;
  __syncthreads();
  for (int s=1;s<1024;s<<=1){
    int t = ((int)threadIdx.x >= s) ? buf[threadIdx.x - s] : 0;
    __syncthreads();
    buf[threadIdx.x] += t;
    __syncthreads();
  }
  if (i<n) off[i] = buf[threadIdx.x] - v;
  if (threadIdx.x==1023) tot[blockIdx.x] = buf[1023];
}

// merged: every block wave-scans tot[] then adds; block 0 writes off[n]=total
__global__ void scan_add2(int* __restrict__ off, int* __restrict__ off_mut,
                          const int* __restrict__ tot, int n, int nb){
  __shared__ int stot[64];
  if (threadIdx.x < 64){
    int lane = (int)threadIdx.x;
    int orig = (lane<nb)? tot[lane] : 0;
    int v = orig;
    for (int s=1;s<64;s<<=1){ int t = __shfl_up(v, s); if (lane>=s) v += t; }
    stot[lane] = v - orig;
    if (lane==63 && blockIdx.x==0) off[n] = v;
  }
  __syncthreads();
  int i = (int)(blockIdx.x*blockDim.x + threadIdx.x);
  if (i<n){
    int v = off[i] + stot[i>>10];
    off[i] = v;
    off_mut[i] = v;
  }
}

__global__ void fill_kernel(const int* __restrict__ src, const int* __restrict__ dst,
                            int* __restrict__ off_mut, int* __restrict__ ssrc, int n){
  int e = (int)(blockIdx.x*blockDim.x + threadIdx.x);
  if (e < n){
    int p = atomicAdd(&off_mut[dst[e]], 1);
    ssrc[p] = src[e];
  }
}

// ================= softmax aggregate over edges: 4 edges/iter, 16B gathers ===========
__global__ __launch_bounds__(256)
void agg_edges(const int* __restrict__ off, const int* __restrict__ ssrc,
               const float* __restrict__ ls, const float* __restrict__ ld,
               const unsigned short* __restrict__ Mrows, const float* __restrict__ bias,
               unsigned short* __restrict__ outb, int n)
{
  __shared__ float wbuf[4][64];
  __shared__ int   sbuf[4][64];
  const int ws = (int)(threadIdx.x >> 6);
  int node = (int)((blockIdx.x * blockDim.x + threadIdx.x) >> 6);
  int lane = (int)(threadIdx.x & 63);
  if (node >= n) return;
  int e0 = off[node], e1 = off[node+1];
  float ldv = ld[node];
  const int g4 = lane >> 4, cl = lane & 15;
  float denom = 0.f;
  float acc[8] = {0.f,0.f,0.f,0.f,0.f,0.f,0.f,0.f};
  for (int j0=e0; j0<e1; j0+=64){
    int cnt = min(64, e1-j0);
    float wv = 0.f; int sc = 0;
    if (lane < cnt){
      sc = ssrc[j0+lane];
      wv = __expf(leakyf(ls[sc]+ldv));
    }
    denom += wv;
    wbuf[ws][lane] = wv;
    sbuf[ws][lane] = sc;
#pragma unroll 4
    for (int k4=0;k4<cnt;k4+=4){
      float wk = wbuf[ws][k4+g4];
      int  sck = sbuf[ws][k4+g4];
      uint4 mm = *(const uint4*)(Mrows + (size_t)sck*HID + cl*8);
      acc[0] += wk*bf2f((unsigned short)(mm.x&0xffff));
      acc[1] += wk*bf2f((unsigned short)(mm.x>>16));
      acc[2] += wk*bf2f((unsigned short)(mm.y&0xffff));
      acc[3] += wk*bf2f((unsigned short)(mm.y>>16));
      acc[4] += wk*bf2f((unsigned short)(mm.z&0xffff));
      acc[5] += wk*bf2f((unsigned short)(mm.z>>16));
      acc[6] += wk*bf2f((unsigned short)(mm.w&0xffff));
      acc[7] += wk*bf2f((unsigned short)(mm.w>>16));
    }
  }
#pragma unroll
  for (int j=0;j<8;j++){ acc[j] += __shfl_xor(acc[j], 16); acc[j] += __shfl_xor(acc[j], 32); }
  for (int o=32;o;o>>=1) denom += __shfl_xor(denom, o);
  if (g4==0){
    float inv = frcp(denom + 1e-16f);
    float4 b0 = *(const float4*)(bias + cl*8);
    float4 b1 = *(const float4*)(bias + cl*8 + 4);
    float o0=eluf(acc[0]*inv+b0.x), o1=eluf(acc[1]*inv+b0.y);
    float o2=eluf(acc[2]*inv+b0.z), o3=eluf(acc[3]*inv+b0.w);
    float o4=eluf(acc[4]*inv+b1.x), o5=eluf(acc[5]*inv+b1.y);
    float o6=eluf(acc[6]*inv+b1.z), o7=eluf(acc[7]*inv+b1.w);
    uint4 u;
    u.x = (unsigned)bf16rne(o0) | ((unsigned)bf16rne(o1)<<16);
    u.y = (unsigned)bf16rne(o2) | ((unsigned)bf16rne(o3)<<16);
    u.z = (unsigned)bf16rne(o4) | ((unsigned)bf16rne(o5)<<16);
    u.w = (unsigned)bf16rne(o6) | ((unsigned)bf16rne(o7)<<16);
    *(uint4*)(outb + (size_t)node*HID + cl*8) = u;
  }
}

// ================= fused readout v4: 1024 thr, 8-way sliced loops ====================
__global__ __launch_bounds__(1024)
void readout_all(const int* __restrict__ goff, const float* __restrict__ X,
                 const float* __restrict__ asrc, const unsigned short* __restrict__ Xt,
                 const float* __restrict__ vmd, const float* __restrict__ bm_,
                 const unsigned short* __restrict__ Wit, const unsigned short* __restrict__ Wht,
                 const float* __restrict__ bih, const float* __restrict__ bhh,
                 const float* __restrict__ W2, const float* __restrict__ b2,
                 float* __restrict__ dout)
{
  __shared__ __align__(16) float sh_o[128];
  __shared__ __align__(16) float sh_h[128];
  __shared__ float sp[8][128];
  __shared__ float sg[6][8][128];
  __shared__ float sden[8];
  __shared__ float sred[4];
  const int g = (int)blockIdx.x;
  const int tid = (int)threadIdx.x;
  const int c = tid & 127, s = tid >> 7;       // 8 slices
  const int n0 = goff[g], n1 = goff[g+1];
  const ushort4v* W4i = (const ushort4v*)Wit;
  const ushort4v* W4h = (const ushort4v*)Wht;

  // ---- graph sum + relu (8-way sliced) ----
  float a = 0.f;
  for (int n = n0 + s; n < n1; n += 8) a += X[(size_t)n*HID + c];
  sp[s][c] = a;
  __syncthreads();
  if (s == 0){
    float t0 = sp[0][c]+sp[1][c]+sp[2][c]+sp[3][c];
    float t1 = sp[4][c]+sp[5][c]+sp[6][c]+sp[7][c];
    sh_o[c] = fmaxf(t0+t1, 0.f);
  }
  __syncthreads();

  const float bi0=bih[c], bi1=bih[c+128], bi2=bih[c+256];
  const float bh0=bhh[c], bh1=bhh[c+128], bh2=bhh[c+256];
  const float bmc = bm_[c];

  for (int t=0;t<3;t++){
    if (s == 0){
      float p = sh_o[c]*vmd[c];
      for (int o=32;o;o>>=1) p += __shfl_down(p, o);
      if ((c&63)==0) sred[c>>6] = p;
    }
    __syncthreads();
    float ad = sred[0] + sred[1];
    float den = 0.f, acc = 0.f;
    for (int nn = n0 + s; nn < n1; nn += 8){
      float wv = __expf(leakyf(asrc[nn] + ad));
      den += wv;
      acc += wv * bf2f(Xt[(size_t)nn*HID + c]);
    }
    sp[s][c] = acc;
    if (c == 0) sden[s] = den;
    __syncthreads();
    if (s == 0){
      float dsum = (sden[0]+sden[1]+sden[2]+sden[3])+(sden[4]+sden[5]+sden[6]+sden[7]);
      float asum = (sp[0][c]+sp[1][c]+sp[2][c]+sp[3][c])+(sp[4][c]+sp[5][c]+sp[6][c]+sp[7][c]);
      sh_h[c] = eluf(asum*frcp(dsum + 1e-16f) + bmc);
    }
    __syncthreads();
    // ---- GRU matvec: quad-packed loads, slice owns 4 k-quads ----
    float gi0=0.f,gi1=0.f,gi2=0.f,gh0=0.f,gh1=0.f,gh2=0.f;
    const int q0 = s*4;
#pragma unroll
    for (int q=q0;q<q0+4;q++){
      float4 hk = *(const float4*)&sh_h[q*4];
      float4 ok = *(const float4*)&sh_o[q*4];
      ushort4v wi0 = W4i[(size_t)q*384 + c];
      ushort4v wi1 = W4i[(size_t)q*384 + c + 128];
      ushort4v wi2 = W4i[(size_t)q*384 + c + 256];
      ushort4v wh0 = W4h[(size_t)q*384 + c];
      ushort4v wh1 = W4h[(size_t)q*384 + c + 128];
      ushort4v wh2 = W4h[(size_t)q*384 + c + 256];
      gi0 += bf2f(wi0.x)*hk.x + bf2f(wi0.y)*hk.y + bf2f(wi0.z)*hk.z + bf2f(wi0.w)*hk.w;
      gi1 += bf2f(wi1.x)*hk.x + bf2f(wi1.y)*hk.y + bf2f(wi1.z)*hk.z + bf2f(wi1.w)*hk.w;
      gi2 += bf2f(wi2.x)*hk.x + bf2f(wi2.y)*hk.y + bf2f(wi2.z)*hk.z + bf2f(wi2.w)*hk.w;
      gh0 += bf2f(wh0.x)*ok.x + bf2f(wh0.y)*ok.y + bf2f(wh0.z)*ok.z + bf2f(wh0.w)*ok.w;
      gh1 += bf2f(wh1.x)*ok.x + bf2f(wh1.y)*ok.y + bf2f(wh1.z)*ok.z + bf2f(wh1.w)*ok.w;
      gh2 += bf2f(wh2.x)*ok.x + bf2f(wh2.y)*ok.y + bf2f(wh2.z)*ok.z + bf2f(wh2.w)*ok.w;
    }
    sg[0][s][c]=gi0; sg[1][s][c]=gi1; sg[2][s][c]=gi2;
    sg[3][s][c]=gh0; sg[4][s][c]=gh1; sg[5][s][c]=gh2;
    __syncthreads();
    if (s == 0){
      float G0=0,G1=0,G2=0,H0=0,H1=0,H2=0;
#pragma unroll
      for (int ss=0;ss<8;ss++){
        G0+=sg[0][ss][c]; G1+=sg[1][ss][c]; G2+=sg[2][ss][c];
        H0+=sg[3][ss][c]; H1+=sg[4][ss][c]; H2+=sg[5][ss][c];
      }
      float rr = fsigm(G0+bi0+H0+bh0);
      float zz = fsigm(G1+bi1+H1+bh1);
      float nv = ftanh(G2+bi2 + rr*(H2+bh2));
      sh_o[c] = fmaxf((1.f-zz)*nv + zz*sh_o[c], 0.f);
    }
    __syncthreads();
  }
  if (s == 0){
    float p = sh_o[c]*W2[c];
    for (int o=32;o;o>>=1) p += __shfl_down(p, o);
    if ((c&63)==0) sred[(c>>6)+2] = p;
  }
  __syncthreads();
  if (tid==0) dout[g] = sred[2] + sred[3] + b2[0];
}

// =====================================================================================
extern "C" void kernel_launch(void* const* d_in, const int* in_sizes, int n_in,
                              void* d_out, int out_size, void* d_ws, size_t ws_size,
                              hipStream_t stream)
{
  const float* x_in  = (const float*)d_in[0];
  const int*   ei    = (const int*)d_in[1];
  const int*   batch = (const int*)d_in[2];
  const float* W1    = (const float*)d_in[3];
  const float* b1    = (const float*)d_in[4];
  const float* Wg1   = (const float*)d_in[5];
  const float* att_l = (const float*)d_in[6];
  const float* att_r = (const float*)d_in[7];
  const float* Wg2   = (const float*)d_in[8];
  const float* bg    = (const float*)d_in[9];
  const float* Wih0  = (const float*)d_in[10];
  const float* Whh0  = (const float*)d_in[11];
  const float* bih0  = (const float*)d_in[12];
  const float* bhh0  = (const float*)d_in[13];
  const float* Wa    = (const float*)d_in[14];
  const float* att_src_a = (const float*)d_in[15];
  const float* att_dst_a = (const float*)d_in[16];
  const float* ba    = (const float*)d_in[17];
  const float* Wih_a = (const float*)d_in[18];
  const float* Whh_a = (const float*)d_in[19];
  const float* bih_a = (const float*)d_in[20];
  const float* bhh_a = (const float*)d_in[21];
  const float* Wm    = (const float*)d_in[22];
  const float* att_src_m = (const float*)d_in[23];
  const float* att_dst_m = (const float*)d_in[24];
  const float* bm    = (const float*)d_in[25];
  const float* Wih_m = (const float*)d_in[26];
  const float* Whh_m = (const float*)d_in[27];
  const float* bih_m = (const float*)d_in[28];
  const float* bhh_m = (const float*)d_in[29];
  const float* W2    = (const float*)d_in[30];
  const float* b2    = (const float*)d_in[31];
  (void)in_sizes; (void)n_in; (void)out_size; (void)ws_size;

  char* wsb = (char*)d_ws;
  size_t off = 0;
  auto alloc = [&](size_t bytes)->void* {
    void* p = wsb + off;
    off += (bytes + 255) & ~(size_t)255;
    return p;
  };
  float* f_x   = (float*)alloc((size_t)NN*HID*4);
  float* f_y   = (float*)alloc((size_t)NN*HID*4);
  unsigned short* f_xb = (unsigned short*)alloc((size_t)NN*HID*2);
  unsigned short* f_yb = (unsigned short*)alloc((size_t)NN*HID*2);
  unsigned short* f_h  = (unsigned short*)alloc((size_t)NN*HID*2);
  unsigned short* f_t  = (unsigned short*)alloc((size_t)NN*HID*2);
  float* f_s1  = (float*)alloc((size_t)NN*4);
  float* f_s2  = (float*)alloc((size_t)NN*4);
  float* w_cg  = (float*)alloc((size_t)HID*4);
  float* w_vmd = (float*)alloc((size_t)HID*4);
  unsigned short* w_pack = (unsigned short*)alloc((size_t)385024*2);
  unsigned short* w_wit  = (unsigned short*)alloc((size_t)49152*2);
  unsigned short* w_wht  = (unsigned short*)alloc((size_t)49152*2);
  int* i_cnt   = (int*)alloc((size_t)NN*4);
  int* i_off   = (int*)alloc((size_t)(NN+1)*4);
  int* i_offm  = (int*)alloc((size_t)NN*4);
  int* i_src   = (int*)alloc((size_t)NE*4);
  int* i_tot   = (int*)alloc((size_t)64*4);
  int* i_goff  = (int*)alloc((size_t)(NG+1)*4);

  const unsigned short* pk_W1   = w_pack + 0;
  const unsigned short* pk_g1   = w_pack + 8192;
  const unsigned short* pk_g2   = w_pack + 24576;
  const unsigned short* pk_wa0  = w_pack + 40960;
  const unsigned short* pk_wa1  = w_pack + 57344;
  const unsigned short* pk_wm   = w_pack + 73728;
  const unsigned short* pk_wih0 = w_pack + 90112;
  const unsigned short* pk_whh0 = w_pack + 139264;
  const unsigned short* pk_wiha0= w_pack + 188416;
  const unsigned short* pk_whha0= w_pack + 237568;
  const unsigned short* pk_wiha1= w_pack + 286720;
  const unsigned short* pk_whha1= w_pack + 335872;

  const int* e_src = ei;
  const int* e_dst = ei + NE;

  hipMemsetAsync(i_cnt, 0, (size_t)NN*4, stream);

  const int NB = (NN + 1023)/1024;
  count_kernel<<<(NE+255)/256,256,0,stream>>>(e_dst, i_cnt, NE);
  pack_all<<<dim3(24,14),256,0,stream>>>(W1, Wg1, Wg2, Wa, Wm, Wih0, Whh0,
                                         Wih_a, Whh_a, Wih_m, Whh_m, att_dst_m,
                                         batch, w_pack, w_wit, w_wht,
                                         w_cg, w_vmd, i_goff);
  scan_blocks<<<NB,1024,0,stream>>>(i_cnt, i_off, i_tot, NN);
  scan_add2<<<(NN+255)/256,256,0,stream>>>(i_off, i_offm, i_tot, NN, NB);
  fill_kernel<<<(NE+255)/256,256,0,stream>>>(e_src, e_dst, i_offm, i_src, NE);

  const int GB = (NN+31)/32;
  const int NT = NN/16;
  const int FB = (NT+GRU_TPB-1)/GRU_TPB;

  gemm_f32<<<GB,256,0,stream>>>(x_in, pk_W1, b1, f_x, f_xb, NN, 1);

  float* curf = f_x;  unsigned short* curb = f_xb;
  float* nxtf = f_y;  unsigned short* nxtb = f_yb;

  // ---- GATEConv (merged dual-GEMM) ----
  gemm_gate<<<GB,256,0,stream>>>(curb, pk_g1, pk_g2, w_cg, att_l, att_r,
                                 f_t, f_s1, f_s2, NN);
  agg_edges<<<(NN+3)/4,256,0,stream>>>(i_off, i_src, f_s1, f_s2, f_t, bg, f_h, NN);
  fused_gru<<<FB,512,0,stream>>>(f_h, curb, curf, pk_wih0, pk_whh0, bih0, bhh0,
                                 nxtf, nxtb, NT);
  { float* t=curf; curf=nxtf; nxtf=t; unsigned short* tb=curb; curb=nxtb; nxtb=tb; }

  // ---- 2x GATConv + GRU ----
  for (int l=0;l<2;l++){
    gemm_b16<<<GB,256,0,stream>>>(curb, l ? pk_wa1 : pk_wa0, nullptr, f_t,
                                  att_src_a + l*HID, att_dst_a + l*HID,
                                  f_s1, f_s2, NN, 0);
    agg_edges<<<(NN+3)/4,256,0,stream>>>(i_off, i_src, f_s1, f_s2, f_t, ba + l*HID, f_h, NN);
    fused_gru<<<FB,512,0,stream>>>(f_h, curb, curf,
                                   l ? pk_wiha1 : pk_wiha0, l ? pk_whha1 : pk_whha0,
                                   bih_a + l*384, bhh_a + l*384, nxtf, nxtb, NT);
    { float* t=curf; curf=nxtf; nxtf=t; unsigned short* tb=curb; curb=nxtb; nxtb=tb; }
  }

  // ---- attentive readout (xt GEMM + one fused kernel) ----
  gemm_b16<<<GB,256,0,stream>>>(curb, pk_wm, nullptr, f_t,
                                att_src_m, nullptr, f_s1, nullptr, NN, 0);
  readout_all<<<NG,1024,0,stream>>>(i_goff, curf, f_s1, f_t, w_vmd, bm,
                                    w_wit, w_wht, bih_m, bhh_m, W2, b2,
                                    (float*)d_out);
}

// Round 14
// 595.700 us; speedup vs baseline: 1.1023x; 1.1023x over previous
//
#include <hip/hip_runtime.h>
#include <math.h>

#define NN 50000
#define NE 800000
#define NG 1024
#define HID 128

typedef __attribute__((ext_vector_type(8))) short short8;
typedef __attribute__((ext_vector_type(4))) unsigned short ushort4v;
typedef __attribute__((ext_vector_type(4))) float f32x4;

__device__ __forceinline__ float leakyf(float v){ return v >= 0.f ? v : 0.01f*v; }
__device__ __forceinline__ float frcp(float x){ return __builtin_amdgcn_rcpf(x); }
__device__ __forceinline__ float fsigm(float v){ return frcp(1.f + __expf(-v)); }
__device__ __forceinline__ float ftanh(float v){ return 1.f - 2.f*frcp(1.f + __expf(2.f*v)); }
__device__ __forceinline__ float eluf(float v){ return v > 0.f ? v : __expf(v) - 1.f; }
__device__ __forceinline__ unsigned short bf16rne(float f){
  union { float f; unsigned u; } v; v.f = f;
  return (unsigned short)((v.u + 0x7FFFu + ((v.u >> 16) & 1u)) >> 16);
}
__device__ __forceinline__ float bf2f(unsigned short h){
  union { unsigned u; float f; } v; v.u = ((unsigned)h) << 16; return v.f;
}
__device__ __forceinline__ short8 cvt8(const float* a){
  short8 r;
#pragma unroll
  for (int j=0;j<8;j++) r[j] = (short)bf16rne(a[j]);
  return r;
}

// ======== pack weights + all small prep, one dispatch ================================
// m=0..11: MFMA B-frag packs; m=12: readout GRU k-quad pack; m=13: cg/vmd/goff prep
__global__ __launch_bounds__(256)
void pack_all(const float* W1, const float* Wg1, const float* Wg2, const float* Wa,
              const float* Wm, const float* Wih0, const float* Whh0,
              const float* Wih_a, const float* Whh_a,
              const float* Wih_m, const float* Whh_m, const float* att_dst_m,
              const int* __restrict__ batch,
              unsigned short* __restrict__ dst,
              unsigned short* __restrict__ Wit, unsigned short* __restrict__ Wht,
              float* __restrict__ cg, float* __restrict__ vmd,
              int* __restrict__ goff)
{
  int m = (int)blockIdx.y;
  int tid = (int)threadIdx.x;
  if (m == 12){
    for (int it = (int)blockIdx.x*256 + tid; it < 32*384; it += 24*256){
      int q = it / 384, cg2 = it - q*384;
      ushort4v a, b;
#pragma unroll
      for (int j=0;j<4;j++){
        a[j] = bf16rne(Wih_m[(size_t)cg2*128 + q*4 + j]);
        b[j] = bf16rne(Whh_m[(size_t)cg2*128 + q*4 + j]);
      }
      *(ushort4v*)&Wit[((size_t)q*384 + cg2)*4] = a;
      *(ushort4v*)&Wht[((size_t)q*384 + cg2)*4] = b;
    }
    return;
  }
  if (m == 13){
    if (blockIdx.x == 0){
      if (tid < 128){
        float s = 0.f;
        for (int k=128;k<153;k++) s += Wg1[(size_t)tid*153+k];
        cg[tid] = s;
      } else {
        int k = tid - 128;
        float s = 0.f;
        for (int j=0;j<HID;j++) s += Wm[(size_t)j*HID+k]*att_dst_m[j];
        vmd[k] = s;
      }
    } else {
      int g = ((int)blockIdx.x-1)*256 + tid;
      if (g <= NG){
        int lo=0, hi=NN;
        while (lo<hi){ int mid=(lo+hi)>>1; if (batch[mid] < g) lo=mid+1; else hi=mid; }
        goff[g] = lo;
      }
    }
    return;
  }
  int t = (int)blockIdx.x*4 + (tid>>6);
  int l = tid & 63;
  const float* src; int stride=128, M=128, K=128; size_t doff;
  switch(m){
    case 0:  src=W1;    stride=64;  K=64;  doff=0;      break;
    case 1:  src=Wg1;   stride=153;        doff=8192;   break;
    case 2:  src=Wg2;                      doff=24576;  break;
    case 3:  src=Wa;                       doff=40960;  break;
    case 4:  src=Wa+16384;                 doff=57344;  break;
    case 5:  src=Wm;                       doff=73728;  break;
    case 6:  src=Wih0;  M=384;             doff=90112;  break;
    case 7:  src=Whh0;  M=384;             doff=139264; break;
    case 8:  src=Wih_a; M=384;             doff=188416; break;
    case 9:  src=Whh_a; M=384;             doff=237568; break;
    case 10: src=Wih_a+49152; M=384;       doff=286720; break;
    default: src=Whh_a+49152; M=384;       doff=335872; break;
  }
  int tk = K/32;
  if (t >= (M/16)*tk) return;
  int ct = t / tk, kc = t % tk;
  int row = ct*16 + (l&15);
  int col = kc*32 + ((l>>4)<<3);
  unsigned short o[8];
#pragma unroll
  for (int j=0;j<8;j++) o[j] = bf16rne(src[(size_t)row*stride + col + j]);
  ushort4v* d = (ushort4v*)(dst + doff + (((size_t)t*64 + l)<<3));
  ushort4v d0; d0.x=o[0]; d0.y=o[1]; d0.z=o[2]; d0.w=o[3];
  ushort4v d1; d1.x=o[4]; d1.y=o[5]; d1.z=o[6]; d1.w=o[7];
  d[0]=d0; d[1]=d1;
}

// ======== gemm_f32: fp32 A (first layer only, K=64), dual fp32+bf16 C out ============
__global__ __launch_bounds__(256)
void gemm_f32(const float* __restrict__ A, const unsigned short* __restrict__ Wp,
              const float* __restrict__ bias, float* __restrict__ Cf,
              unsigned short* __restrict__ Cb, int rows, int act)
{
  constexpr int K = 64, KC = 2;
  const int tid=(int)threadIdx.x, w=tid>>6, l=tid&63;
  const int fr=l&15, fq=l>>4;
  const int rt=w>>1, ch=w&1;
  const int bn = (int)blockIdx.x*32;
  const int ar = bn + rt*16 + fr;
  f32x4 acc[4];
#pragma unroll
  for (int j=0;j<4;j++) acc[j] = (f32x4){0.f,0.f,0.f,0.f};
#pragma unroll
  for (int kc=0;kc<KC;kc++){
    float a8[8];
    if (ar < rows){
      *(float4*)&a8[0] = *(const float4*)(A + (size_t)ar*K + kc*32 + fq*8);
      *(float4*)&a8[4] = *(const float4*)(A + (size_t)ar*K + kc*32 + fq*8 + 4);
    } else {
#pragma unroll
      for (int j=0;j<8;j++) a8[j]=0.f;
    }
    short8 fa = cvt8(a8);
#pragma unroll
    for (int j=0;j<4;j++){
      const short8 bfr = *(const short8*)(Wp + ((((size_t)(ch*4+j)*KC + kc)*64 + l)<<3));
      acc[j] = __builtin_amdgcn_mfma_f32_16x16x32_bf16(fa, bfr, acc[j], 0, 0, 0);
    }
  }
#pragma unroll
  for (int j=0;j<4;j++){
    int c = ch*64 + j*16 + fr;
    float bv = bias ? bias[c] : 0.f;
#pragma unroll
    for (int r4=0;r4<4;r4++){
      float o = acc[j][r4] + bv;
      if (act) o = leakyf(o);
      int r = bn + rt*16 + fq*4 + r4;
      if (r < rows){
        Cf[(size_t)r*HID + c] = o;
        Cb[(size_t)r*HID + c] = bf16rne(o);
      }
    }
  }
}

// ======== gemm_b16: bf16 A (128-K), optional bf16 C, fused attention dots ============
__global__ __launch_bounds__(256)
void gemm_b16(const unsigned short* __restrict__ Ab, const unsigned short* __restrict__ Wp,
              const float* __restrict__ bias, unsigned short* __restrict__ Cb,
              const float* __restrict__ v1, const float* __restrict__ v2,
              float* __restrict__ s1, float* __restrict__ s2, int rows, int act)
{
  __shared__ float sd1[2][32];
  __shared__ float sd2[2][32];
  constexpr int KC = 4;
  const int tid=(int)threadIdx.x, w=tid>>6, l=tid&63;
  const int fr=l&15, fq=l>>4;
  const int rt=w>>1, ch=w&1;
  const int bn = (int)blockIdx.x*32;
  const int ar = bn + rt*16 + fr;
  f32x4 acc[4];
#pragma unroll
  for (int j=0;j<4;j++) acc[j] = (f32x4){0.f,0.f,0.f,0.f};
#pragma unroll
  for (int kc=0;kc<KC;kc++){
    short8 fa;
    if (ar < rows) fa = *(const short8*)(Ab + (size_t)ar*HID + kc*32 + fq*8);
    else { short8 z = {0,0,0,0,0,0,0,0}; fa = z; }
#pragma unroll
    for (int j=0;j<4;j++){
      const short8 bfr = *(const short8*)(Wp + ((((size_t)(ch*4+j)*KC + kc)*64 + l)<<3));
      acc[j] = __builtin_amdgcn_mfma_f32_16x16x32_bf16(fa, bfr, acc[j], 0, 0, 0);
    }
  }
  float dp1[4]={0.f,0.f,0.f,0.f}, dp2[4]={0.f,0.f,0.f,0.f};
#pragma unroll
  for (int j=0;j<4;j++){
    int c = ch*64 + j*16 + fr;
    float bv = bias ? bias[c] : 0.f;
    float w1 = v1 ? v1[c] : 0.f;
    float w2 = v2 ? v2[c] : 0.f;
#pragma unroll
    for (int r4=0;r4<4;r4++){
      float o = acc[j][r4] + bv;
      if (act) o = leakyf(o);
      dp1[r4] += o*w1; dp2[r4] += o*w2;
      int r = bn + rt*16 + fq*4 + r4;
      if (r < rows && Cb) Cb[(size_t)r*HID + c] = bf16rne(o);
    }
  }
  if (v1){
#pragma unroll
    for (int r4=0;r4<4;r4++){
#pragma unroll
      for (int m=1;m<16;m<<=1){ dp1[r4] += __shfl_xor(dp1[r4], m); dp2[r4] += __shfl_xor(dp2[r4], m); }
    }
    if (fr==0){
#pragma unroll
      for (int r4=0;r4<4;r4++){
        sd1[ch][rt*16 + fq*4 + r4] = dp1[r4];
        sd2[ch][rt*16 + fq*4 + r4] = dp2[r4];
      }
    }
    __syncthreads();
    if (tid < 32){
      int r = bn + tid;
      if (r < rows) s1[r] = sd1[0][tid] + sd1[1][tid];
    } else if (v2 && tid < 64){
      int r = bn + tid - 32;
      if (r < rows) s2[r] = sd2[0][tid-32] + sd2[1][tid-32];
    }
  }
}

// ======== gemm_gate: GATEConv merged pass ===========================================
__global__ __launch_bounds__(256)
void gemm_gate(const unsigned short* __restrict__ Ab,
               const unsigned short* __restrict__ W1p, const unsigned short* __restrict__ W2p,
               const float* __restrict__ cg, const float* __restrict__ attl,
               const float* __restrict__ attr,
               unsigned short* __restrict__ Cb,
               float* __restrict__ s1, float* __restrict__ s2, int rows)
{
  __shared__ float sd1[2][32];
  constexpr int KC = 4;
  const int tid=(int)threadIdx.x, w=tid>>6, l=tid&63;
  const int fr=l&15, fq=l>>4;
  const int rt=w>>1, ch=w&1;
  const int bn = (int)blockIdx.x*32;
  const int ar = bn + rt*16 + fr;
  f32x4 acc1[4], acc2[4];
#pragma unroll
  for (int j=0;j<4;j++){ acc1[j]=(f32x4){0,0,0,0}; acc2[j]=(f32x4){0,0,0,0}; }
  float pa = 0.f;
#pragma unroll
  for (int kc=0;kc<KC;kc++){
    short8 fa;
    if (ar < rows) fa = *(const short8*)(Ab + (size_t)ar*HID + kc*32 + fq*8);
    else { short8 z = {0,0,0,0,0,0,0,0}; fa = z; }
    if (ch==0){
      float4 t0 = *(const float4*)(attr + kc*32 + fq*8);
      float4 t1 = *(const float4*)(attr + kc*32 + fq*8 + 4);
      pa += bf2f((unsigned short)fa[0])*t0.x + bf2f((unsigned short)fa[1])*t0.y
          + bf2f((unsigned short)fa[2])*t0.z + bf2f((unsigned short)fa[3])*t0.w
          + bf2f((unsigned short)fa[4])*t1.x + bf2f((unsigned short)fa[5])*t1.y
          + bf2f((unsigned short)fa[6])*t1.z + bf2f((unsigned short)fa[7])*t1.w;
    }
#pragma unroll
    for (int j=0;j<4;j++){
      size_t wo = ((((size_t)(ch*4+j)*KC + kc)*64 + l)<<3);
      acc1[j] = __builtin_amdgcn_mfma_f32_16x16x32_bf16(fa, *(const short8*)(W1p + wo), acc1[j], 0, 0, 0);
      acc2[j] = __builtin_amdgcn_mfma_f32_16x16x32_bf16(fa, *(const short8*)(W2p + wo), acc2[j], 0, 0, 0);
    }
  }
  float dp1[4]={0.f,0.f,0.f,0.f};
#pragma unroll
  for (int j=0;j<4;j++){
    int c = ch*64 + j*16 + fr;
    float bv = cg[c];
    float w1 = attl[c];
#pragma unroll
    for (int r4=0;r4<4;r4++){
      float o1 = leakyf(acc1[j][r4] + bv);
      dp1[r4] += o1*w1;
      int r = bn + rt*16 + fq*4 + r4;
      if (r < rows) Cb[(size_t)r*HID + c] = bf16rne(acc2[j][r4]);
    }
  }
#pragma unroll
  for (int r4=0;r4<4;r4++){
#pragma unroll
    for (int m=1;m<16;m<<=1) dp1[r4] += __shfl_xor(dp1[r4], m);
  }
  if (fr==0){
#pragma unroll
    for (int r4=0;r4<4;r4++) sd1[ch][rt*16 + fq*4 + r4] = dp1[r4];
  }
  __syncthreads();
  if (tid < 32){
    int r = bn + tid;
    if (r < rows) s1[r] = sd1[0][tid] + sd1[1][tid];
  }
  if (ch==0){
    pa += __shfl_xor(pa, 16); pa += __shfl_xor(pa, 32);
    if (fq==0){
      int r = bn + rt*16 + fr;
      if (r < rows) s2[r] = pa;
    }
  }
}

// ======== fused GRU: reg weights, 4 tiles/block, full prefetch (incl. hv) ===========
#define GRU_TPB 4
__global__ __launch_bounds__(512, 2)
void fused_gru(const unsigned short* __restrict__ Ahb, const unsigned short* __restrict__ Axb,
               const float* __restrict__ Axf,
               const unsigned short* __restrict__ Wi, const unsigned short* __restrict__ Wh,
               const float* __restrict__ bih, const float* __restrict__ bhh,
               float* __restrict__ outf, unsigned short* __restrict__ outb, int tiles)
{
  const int tid=(int)threadIdx.x, w=tid>>6, l=tid&63;
  const int fr=l&15, fq=l>>4;
  short8 wi_r[3][4], wh_r[3][4];
#pragma unroll
  for (int g=0;g<3;g++)
#pragma unroll
    for (int kc=0;kc<4;kc++){
      size_t o = ((((size_t)(g*8 + w)*4 + kc)*64 + l)<<3);
      wi_r[g][kc] = *(const short8*)(Wi + o);
      wh_r[g][kc] = *(const short8*)(Wh + o);
    }
  const int c0 = w*16 + fr;
  float bi0=bih[c0], bi1=bih[c0+128], bi2=bih[c0+256];
  float bh0=bhh[c0], bh1=bhh[c0+128], bh2=bhh[c0+256];

  int rt = (int)blockIdx.x*GRU_TPB;
  int rt_end = min(rt + GRU_TPB, tiles);
  if (rt >= tiles) return;
  short8 fa[4], fx[4];
  float hv[4];
  {
    const int arow = rt*16 + fr;
#pragma unroll
    for (int kc=0;kc<4;kc++){
      fa[kc] = *(const short8*)(Ahb + (size_t)arow*HID + kc*32 + fq*8);
      fx[kc] = *(const short8*)(Axb + (size_t)arow*HID + kc*32 + fq*8);
    }
#pragma unroll
    for (int r4=0;r4<4;r4++) hv[r4] = Axf[(size_t)(rt*16 + fq*4 + r4)*HID + c0];
  }
  for (; rt < rt_end; rt++){
    short8 nfa[4], nfx[4];
    float nhv[4];
    if (rt+1 < rt_end){
      const int arow = (rt+1)*16 + fr;
#pragma unroll
      for (int kc=0;kc<4;kc++){
        nfa[kc] = *(const short8*)(Ahb + (size_t)arow*HID + kc*32 + fq*8);
        nfx[kc] = *(const short8*)(Axb + (size_t)arow*HID + kc*32 + fq*8);
      }
#pragma unroll
      for (int r4=0;r4<4;r4++) nhv[r4] = Axf[(size_t)((rt+1)*16 + fq*4 + r4)*HID + c0];
    }
    f32x4 ai0={0,0,0,0}, ai1={0,0,0,0}, ai2={0,0,0,0};
    f32x4 ah0={0,0,0,0}, ah1={0,0,0,0}, ah2={0,0,0,0};
#pragma unroll
    for (int kc=0;kc<4;kc++){
      ai0 = __builtin_amdgcn_mfma_f32_16x16x32_bf16(fa[kc], wi_r[0][kc], ai0, 0, 0, 0);
      ai1 = __builtin_amdgcn_mfma_f32_16x16x32_bf16(fa[kc], wi_r[1][kc], ai1, 0, 0, 0);
      ai2 = __builtin_amdgcn_mfma_f32_16x16x32_bf16(fa[kc], wi_r[2][kc], ai2, 0, 0, 0);
      ah0 = __builtin_amdgcn_mfma_f32_16x16x32_bf16(fx[kc], wh_r[0][kc], ah0, 0, 0, 0);
      ah1 = __builtin_amdgcn_mfma_f32_16x16x32_bf16(fx[kc], wh_r[1][kc], ah1, 0, 0, 0);
      ah2 = __builtin_amdgcn_mfma_f32_16x16x32_bf16(fx[kc], wh_r[2][kc], ah2, 0, 0, 0);
    }
#pragma unroll
    for (int r4=0;r4<4;r4++){
      int row = rt*16 + fq*4 + r4;
      float rr = fsigm(ai0[r4] + bi0 + ah0[r4] + bh0);
      float zz = fsigm(ai1[r4] + bi1 + ah1[r4] + bh1);
      float nn = ftanh(ai2[r4] + bi2 + rr*(ah2[r4] + bh2));
      float o = fmaxf((1.f - zz)*nn + zz*hv[r4], 0.f);
      outf[(size_t)row*HID + c0] = o;
      outb[(size_t)row*HID + c0] = bf16rne(o);
    }
#pragma unroll
    for (int kc=0;kc<4;kc++){ fa[kc]=nfa[kc]; fx[kc]=nfx[kc]; }
#pragma unroll
    for (int r4=0;r4<4;r4++) hv[r4]=nhv[r4];
  }
}

// ================= CSR build =========================================================
__global__ void count_kernel(const int* __restrict__ idx, int* __restrict__ cnt, int n){
  int i = (int)(blockIdx.x*blockDim.x + threadIdx.x);
  if (i < n) atomicAdd(&cnt[idx[i]], 1);
}

__global__ __launch_bounds__(1024)
void scan_blocks(const int* __restrict__ cnt, int* __restrict__ off,
                 int* __restrict__ tot, int n)
{
  __shared__ int buf[1024];
  int i = (int)(blockIdx.x*1024 + threadIdx.x);
  int v = (i<n)? cnt[i] : 0;
  buf[threadIdx.x] = v;
  __syncthreads();
  for (int s=1;s<1024;s<<=1){
    int t = ((int)threadIdx.x >= s) ? buf[threadIdx.x - s] : 0;
    __syncthreads();
    buf[threadIdx.x] += t;
    __syncthreads();
  }
  if (i<n) off[i] = buf[threadIdx.x] - v;
  if (threadIdx.x==1023) tot[blockIdx.x] = buf[1023];
}

// merged: every block wave-scans tot[] then adds; block 0 writes off[n]=total
__global__ void scan_add2(int* __restrict__ off, int* __restrict__ off_mut,
                          const int* __restrict__ tot, int n, int nb){
  __shared__ int stot[64];
  if (threadIdx.x < 64){
    int lane = (int)threadIdx.x;
    int orig = (lane<nb)? tot[lane] : 0;
    int v = orig;
    for (int s=1;s<64;s<<=1){ int t = __shfl_up(v, s); if (lane>=s) v += t; }
    stot[lane] = v - orig;
    if (lane==63 && blockIdx.x==0) off[n] = v;
  }
  __syncthreads();
  int i = (int)(blockIdx.x*blockDim.x + threadIdx.x);
  if (i<n){
    int v = off[i] + stot[i>>10];
    off[i] = v;
    off_mut[i] = v;
  }
}

__global__ void fill_kernel(const int* __restrict__ src, const int* __restrict__ dst,
                            int* __restrict__ off_mut, int* __restrict__ ssrc, int n){
  int e = (int)(blockIdx.x*blockDim.x + threadIdx.x);
  if (e < n){
    int p = atomicAdd(&off_mut[dst[e]], 1);
    ssrc[p] = src[e];
  }
}

// ================= softmax aggregate over edges: 4 edges/iter, 16B gathers ===========
__global__ __launch_bounds__(256)
void agg_edges(const int* __restrict__ off, const int* __restrict__ ssrc,
               const float* __restrict__ ls, const float* __restrict__ ld,
               const unsigned short* __restrict__ Mrows, const float* __restrict__ bias,
               unsigned short* __restrict__ outb, int n)
{
  __shared__ float wbuf[4][64];
  __shared__ int   sbuf[4][64];
  const int ws = (int)(threadIdx.x >> 6);
  int node = (int)((blockIdx.x * blockDim.x + threadIdx.x) >> 6);
  int lane = (int)(threadIdx.x & 63);
  if (node >= n) return;
  int e0 = off[node], e1 = off[node+1];
  float ldv = ld[node];
  const int g4 = lane >> 4, cl = lane & 15;
  float denom = 0.f;
  float acc[8] = {0.f,0.f,0.f,0.f,0.f,0.f,0.f,0.f};
  for (int j0=e0; j0<e1; j0+=64){
    int cnt = min(64, e1-j0);
    float wv = 0.f; int sc = 0;
    if (lane < cnt){
      sc = ssrc[j0+lane];
      wv = __expf(leakyf(ls[sc]+ldv));
    }
    denom += wv;
    wbuf[ws][lane] = wv;
    sbuf[ws][lane] = sc;
#pragma unroll 4
    for (int k4=0;k4<cnt;k4+=4){
      float wk = wbuf[ws][k4+g4];
      int  sck = sbuf[ws][k4+g4];
      uint4 mm = *(const uint4*)(Mrows + (size_t)sck*HID + cl*8);
      acc[0] += wk*bf2f((unsigned short)(mm.x&0xffff));
      acc[1] += wk*bf2f((unsigned short)(mm.x>>16));
      acc[2] += wk*bf2f((unsigned short)(mm.y&0xffff));
      acc[3] += wk*bf2f((unsigned short)(mm.y>>16));
      acc[4] += wk*bf2f((unsigned short)(mm.z&0xffff));
      acc[5] += wk*bf2f((unsigned short)(mm.z>>16));
      acc[6] += wk*bf2f((unsigned short)(mm.w&0xffff));
      acc[7] += wk*bf2f((unsigned short)(mm.w>>16));
    }
  }
#pragma unroll
  for (int j=0;j<8;j++){ acc[j] += __shfl_xor(acc[j], 16); acc[j] += __shfl_xor(acc[j], 32); }
  for (int o=32;o;o>>=1) denom += __shfl_xor(denom, o);
  if (g4==0){
    float inv = frcp(denom + 1e-16f);
    float4 b0 = *(const float4*)(bias + cl*8);
    float4 b1 = *(const float4*)(bias + cl*8 + 4);
    float o0=eluf(acc[0]*inv+b0.x), o1=eluf(acc[1]*inv+b0.y);
    float o2=eluf(acc[2]*inv+b0.z), o3=eluf(acc[3]*inv+b0.w);
    float o4=eluf(acc[4]*inv+b1.x), o5=eluf(acc[5]*inv+b1.y);
    float o6=eluf(acc[6]*inv+b1.z), o7=eluf(acc[7]*inv+b1.w);
    uint4 u;
    u.x = (unsigned)bf16rne(o0) | ((unsigned)bf16rne(o1)<<16);
    u.y = (unsigned)bf16rne(o2) | ((unsigned)bf16rne(o3)<<16);
    u.z = (unsigned)bf16rne(o4) | ((unsigned)bf16rne(o5)<<16);
    u.w = (unsigned)bf16rne(o6) | ((unsigned)bf16rne(o7)<<16);
    *(uint4*)(outb + (size_t)node*HID + cl*8) = u;
  }
}

// ================= fused readout (v3): 512 thr, quad-packed GRU weights ==============
__global__ __launch_bounds__(512)
void readout_all(const int* __restrict__ goff, const float* __restrict__ X,
                 const float* __restrict__ asrc, const unsigned short* __restrict__ Xt,
                 const float* __restrict__ vmd, const float* __restrict__ bm_,
                 const unsigned short* __restrict__ Wit, const unsigned short* __restrict__ Wht,
                 const float* __restrict__ bih, const float* __restrict__ bhh,
                 const float* __restrict__ W2, const float* __restrict__ b2,
                 float* __restrict__ dout)
{
  __shared__ __align__(16) float sh_o[128];
  __shared__ __align__(16) float sh_h[128];
  __shared__ float sp[4][128];
  __shared__ float sg[6][4][128];
  __shared__ float sden[4];
  __shared__ float sred[4];
  const int g = (int)blockIdx.x;
  const int tid = (int)threadIdx.x;
  const int c = tid & 127, s = tid >> 7;
  const int n0 = goff[g], n1 = goff[g+1];
  const ushort4v* W4i = (const ushort4v*)Wit;
  const ushort4v* W4h = (const ushort4v*)Wht;

  // ---- graph sum + relu (slice-strided) ----
  float a = 0.f;
  for (int n = n0 + s; n < n1; n += 4) a += X[(size_t)n*HID + c];
  sp[s][c] = a;
  __syncthreads();
  if (s == 0)
    sh_o[c] = fmaxf(sp[0][c]+sp[1][c]+sp[2][c]+sp[3][c], 0.f);
  __syncthreads();

  const float bi0=bih[c], bi1=bih[c+128], bi2=bih[c+256];
  const float bh0=bhh[c], bh1=bhh[c+128], bh2=bhh[c+256];
  const float bmc = bm_[c];

  for (int t=0;t<3;t++){
    if (s == 0){
      float p = sh_o[c]*vmd[c];
      for (int o=32;o;o>>=1) p += __shfl_down(p, o);
      if ((c&63)==0) sred[c>>6] = p;
    }
    __syncthreads();
    float ad = sred[0] + sred[1];
    float den = 0.f, acc = 0.f;
    for (int nn = n0 + s; nn < n1; nn += 4){
      float wv = __expf(leakyf(asrc[nn] + ad));
      den += wv;
      acc += wv * bf2f(Xt[(size_t)nn*HID + c]);
    }
    sp[s][c] = acc;
    if (c == 0) sden[s] = den;
    __syncthreads();
    if (s == 0){
      float dsum = sden[0]+sden[1]+sden[2]+sden[3];
      float asum = sp[0][c]+sp[1][c]+sp[2][c]+sp[3][c];
      sh_h[c] = eluf(asum*frcp(dsum + 1e-16f) + bmc);
    }
    __syncthreads();
    // ---- GRU matvec: quad-packed loads, slice owns 8 k-quads ----
    float gi0=0.f,gi1=0.f,gi2=0.f,gh0=0.f,gh1=0.f,gh2=0.f;
    const int q0 = s*8;
#pragma unroll 2
    for (int q=q0;q<q0+8;q++){
      float4 hk = *(const float4*)&sh_h[q*4];
      float4 ok = *(const float4*)&sh_o[q*4];
      ushort4v wi0 = W4i[(size_t)q*384 + c];
      ushort4v wi1 = W4i[(size_t)q*384 + c + 128];
      ushort4v wi2 = W4i[(size_t)q*384 + c + 256];
      ushort4v wh0 = W4h[(size_t)q*384 + c];
      ushort4v wh1 = W4h[(size_t)q*384 + c + 128];
      ushort4v wh2 = W4h[(size_t)q*384 + c + 256];
      gi0 += bf2f(wi0.x)*hk.x + bf2f(wi0.y)*hk.y + bf2f(wi0.z)*hk.z + bf2f(wi0.w)*hk.w;
      gi1 += bf2f(wi1.x)*hk.x + bf2f(wi1.y)*hk.y + bf2f(wi1.z)*hk.z + bf2f(wi1.w)*hk.w;
      gi2 += bf2f(wi2.x)*hk.x + bf2f(wi2.y)*hk.y + bf2f(wi2.z)*hk.z + bf2f(wi2.w)*hk.w;
      gh0 += bf2f(wh0.x)*ok.x + bf2f(wh0.y)*ok.y + bf2f(wh0.z)*ok.z + bf2f(wh0.w)*ok.w;
      gh1 += bf2f(wh1.x)*ok.x + bf2f(wh1.y)*ok.y + bf2f(wh1.z)*ok.z + bf2f(wh1.w)*ok.w;
      gh2 += bf2f(wh2.x)*ok.x + bf2f(wh2.y)*ok.y + bf2f(wh2.z)*ok.z + bf2f(wh2.w)*ok.w;
    }
    sg[0][s][c]=gi0; sg[1][s][c]=gi1; sg[2][s][c]=gi2;
    sg[3][s][c]=gh0; sg[4][s][c]=gh1; sg[5][s][c]=gh2;
    __syncthreads();
    if (s == 0){
      float G0=sg[0][0][c]+sg[0][1][c]+sg[0][2][c]+sg[0][3][c];
      float G1=sg[1][0][c]+sg[1][1][c]+sg[1][2][c]+sg[1][3][c];
      float G2=sg[2][0][c]+sg[2][1][c]+sg[2][2][c]+sg[2][3][c];
      float H0=sg[3][0][c]+sg[3][1][c]+sg[3][2][c]+sg[3][3][c];
      float H1=sg[4][0][c]+sg[4][1][c]+sg[4][2][c]+sg[4][3][c];
      float H2=sg[5][0][c]+sg[5][1][c]+sg[5][2][c]+sg[5][3][c];
      float rr = fsigm(G0+bi0+H0+bh0);
      float zz = fsigm(G1+bi1+H1+bh1);
      float nv = ftanh(G2+bi2 + rr*(H2+bh2));
      sh_o[c] = fmaxf((1.f-zz)*nv + zz*sh_o[c], 0.f);
    }
    __syncthreads();
  }
  if (s == 0){
    float p = sh_o[c]*W2[c];
    for (int o=32;o;o>>=1) p += __shfl_down(p, o);
    if ((c&63)==0) sred[(c>>6)+2] = p;
  }
  __syncthreads();
  if (tid==0) dout[g] = sred[2] + sred[3] + b2[0];
}

// =====================================================================================
extern "C" void kernel_launch(void* const* d_in, const int* in_sizes, int n_in,
                              void* d_out, int out_size, void* d_ws, size_t ws_size,
                              hipStream_t stream)
{
  const float* x_in  = (const float*)d_in[0];
  const int*   ei    = (const int*)d_in[1];
  const int*   batch = (const int*)d_in[2];
  const float* W1    = (const float*)d_in[3];
  const float* b1    = (const float*)d_in[4];
  const float* Wg1   = (const float*)d_in[5];
  const float* att_l = (const float*)d_in[6];
  const float* att_r = (const float*)d_in[7];
  const float* Wg2   = (const float*)d_in[8];
  const float* bg    = (const float*)d_in[9];
  const float* Wih0  = (const float*)d_in[10];
  const float* Whh0  = (const float*)d_in[11];
  const float* bih0  = (const float*)d_in[12];
  const float* bhh0  = (const float*)d_in[13];
  const float* Wa    = (const float*)d_in[14];
  const float* att_src_a = (const float*)d_in[15];
  const float* att_dst_a = (const float*)d_in[16];
  const float* ba    = (const float*)d_in[17];
  const float* Wih_a = (const float*)d_in[18];
  const float* Whh_a = (const float*)d_in[19];
  const float* bih_a = (const float*)d_in[20];
  const float* bhh_a = (const float*)d_in[21];
  const float* Wm    = (const float*)d_in[22];
  const float* att_src_m = (const float*)d_in[23];
  const float* att_dst_m = (const float*)d_in[24];
  const float* bm    = (const float*)d_in[25];
  const float* Wih_m = (const float*)d_in[26];
  const float* Whh_m = (const float*)d_in[27];
  const float* bih_m = (const float*)d_in[28];
  const float* bhh_m = (const float*)d_in[29];
  const float* W2    = (const float*)d_in[30];
  const float* b2    = (const float*)d_in[31];
  (void)in_sizes; (void)n_in; (void)out_size; (void)ws_size;

  char* wsb = (char*)d_ws;
  size_t off = 0;
  auto alloc = [&](size_t bytes)->void* {
    void* p = wsb + off;
    off += (bytes + 255) & ~(size_t)255;
    return p;
  };
  float* f_x   = (float*)alloc((size_t)NN*HID*4);
  float* f_y   = (float*)alloc((size_t)NN*HID*4);
  unsigned short* f_xb = (unsigned short*)alloc((size_t)NN*HID*2);
  unsigned short* f_yb = (unsigned short*)alloc((size_t)NN*HID*2);
  unsigned short* f_h  = (unsigned short*)alloc((size_t)NN*HID*2);
  unsigned short* f_t  = (unsigned short*)alloc((size_t)NN*HID*2);
  float* f_s1  = (float*)alloc((size_t)NN*4);
  float* f_s2  = (float*)alloc((size_t)NN*4);
  float* w_cg  = (float*)alloc((size_t)HID*4);
  float* w_vmd = (float*)alloc((size_t)HID*4);
  unsigned short* w_pack = (unsigned short*)alloc((size_t)385024*2);
  unsigned short* w_wit  = (unsigned short*)alloc((size_t)49152*2);
  unsigned short* w_wht  = (unsigned short*)alloc((size_t)49152*2);
  int* i_cnt   = (int*)alloc((size_t)NN*4);
  int* i_off   = (int*)alloc((size_t)(NN+1)*4);
  int* i_offm  = (int*)alloc((size_t)NN*4);
  int* i_src   = (int*)alloc((size_t)NE*4);
  int* i_tot   = (int*)alloc((size_t)64*4);
  int* i_goff  = (int*)alloc((size_t)(NG+1)*4);

  const unsigned short* pk_W1   = w_pack + 0;
  const unsigned short* pk_g1   = w_pack + 8192;
  const unsigned short* pk_g2   = w_pack + 24576;
  const unsigned short* pk_wa0  = w_pack + 40960;
  const unsigned short* pk_wa1  = w_pack + 57344;
  const unsigned short* pk_wm   = w_pack + 73728;
  const unsigned short* pk_wih0 = w_pack + 90112;
  const unsigned short* pk_whh0 = w_pack + 139264;
  const unsigned short* pk_wiha0= w_pack + 188416;
  const unsigned short* pk_whha0= w_pack + 237568;
  const unsigned short* pk_wiha1= w_pack + 286720;
  const unsigned short* pk_whha1= w_pack + 335872;

  const int* e_src = ei;
  const int* e_dst = ei + NE;

  hipMemsetAsync(i_cnt, 0, (size_t)NN*4, stream);

  const int NB = (NN + 1023)/1024;
  count_kernel<<<(NE+255)/256,256,0,stream>>>(e_dst, i_cnt, NE);
  pack_all<<<dim3(24,14),256,0,stream>>>(W1, Wg1, Wg2, Wa, Wm, Wih0, Whh0,
                                         Wih_a, Whh_a, Wih_m, Whh_m, att_dst_m,
                                         batch, w_pack, w_wit, w_wht,
                                         w_cg, w_vmd, i_goff);
  scan_blocks<<<NB,1024,0,stream>>>(i_cnt, i_off, i_tot, NN);
  scan_add2<<<(NN+255)/256,256,0,stream>>>(i_off, i_offm, i_tot, NN, NB);
  fill_kernel<<<(NE+255)/256,256,0,stream>>>(e_src, e_dst, i_offm, i_src, NE);

  const int GB = (NN+31)/32;
  const int NT = NN/16;
  const int FB = (NT+GRU_TPB-1)/GRU_TPB;

  gemm_f32<<<GB,256,0,stream>>>(x_in, pk_W1, b1, f_x, f_xb, NN, 1);

  float* curf = f_x;  unsigned short* curb = f_xb;
  float* nxtf = f_y;  unsigned short* nxtb = f_yb;

  // ---- GATEConv (merged dual-GEMM) ----
  gemm_gate<<<GB,256,0,stream>>>(curb, pk_g1, pk_g2, w_cg, att_l, att_r,
                                 f_t, f_s1, f_s2, NN);
  agg_edges<<<(NN+3)/4,256,0,stream>>>(i_off, i_src, f_s1, f_s2, f_t, bg, f_h, NN);
  fused_gru<<<FB,512,0,stream>>>(f_h, curb, curf, pk_wih0, pk_whh0, bih0, bhh0,
                                 nxtf, nxtb, NT);
  { float* t=curf; curf=nxtf; nxtf=t; unsigned short* tb=curb; curb=nxtb; nxtb=tb; }

  // ---- 2x GATConv + GRU ----
  for (int l=0;l<2;l++){
    gemm_b16<<<GB,256,0,stream>>>(curb, l ? pk_wa1 : pk_wa0, nullptr, f_t,
                                  att_src_a + l*HID, att_dst_a + l*HID,
                                  f_s1, f_s2, NN, 0);
    agg_edges<<<(NN+3)/4,256,0,stream>>>(i_off, i_src, f_s1, f_s2, f_t, ba + l*HID, f_h, NN);
    fused_gru<<<FB,512,0,stream>>>(f_h, curb, curf,
                                   l ? pk_wiha1 : pk_wiha0, l ? pk_whha1 : pk_whha0,
                                   bih_a + l*384, bhh_a + l*384, nxtf, nxtb, NT);
    { float* t=curf; curf=nxtf; nxtf=t; unsigned short* tb=curb; curb=nxtb; nxtb=tb; }
  }

  // ---- attentive readout (xt GEMM + one fused kernel) ----
  gemm_b16<<<GB,256,0,stream>>>(curb, pk_wm, nullptr, f_t,
                                att_src_m, nullptr, f_s1, nullptr, NN, 0);
  readout_all<<<NG,512,0,stream>>>(i_goff, curf, f_s1, f_t, w_vmd, bm,
                                   w_wit, w_wht, bih_m, bhh_m, W2, b2,
                                   (float*)d_out);
}